// Round 4
// baseline (6837.975 us; speedup 1.0000x reference)
//
#include <hip/hip_runtime.h>
#include <cstdint>

#define TT 256
#define BB 8
#define NE 64
#define HH 512
#define VOCAB 32000
#define G4 2048
#define RS 32064          // out0 row stride (V + NE)
#define MROWS 2048        // B*T
#define LWG 32            // lstm workgroups (sync domain)
#define WSTR 1048         // LDS row stride (halves): 1024 + 24 pad (bank shift 12 dw/row)
#define SCALE 0.044194173824159216f  // 1/sqrt(512)

typedef _Float16 h2 __attribute__((ext_vector_type(2)));
typedef _Float16 h8 __attribute__((ext_vector_type(8)));
typedef float f4 __attribute__((ext_vector_type(4)));

__device__ inline float sigf(float x){ return 1.f/(1.f+__expf(-x)); }

// agent-scope cache-bypassing 64-bit accessors (coherent point, atomic payload+epoch)
__device__ inline unsigned long long g64load(const unsigned long long* p){
  return __hip_atomic_load((unsigned long long*)p, __ATOMIC_RELAXED, __HIP_MEMORY_SCOPE_AGENT);
}
__device__ inline void g64store(unsigned long long* p, unsigned long long v){
  __hip_atomic_store(p, v, __ATOMIC_RELAXED, __HIP_MEMORY_SCOPE_AGENT);
}

// ---------------- casts (f32 -> f16, hi or lo residual) ----------------
__global__ __launch_bounds__(256) void cast_k(const float* __restrict__ src, _Float16* __restrict__ dst,
    int total, int src_ld, int src_off, int dst_ld, int dst_off, int cshift, int lo)
{
  int i = blockIdx.x*256 + threadIdx.x;
  if (i >= total) return;
  int c = i & ((1<<cshift)-1);
  int r = i >> cshift;
  float x = src[(long)r*src_ld + src_off + c];
  _Float16 h = (_Float16)x;
  if (lo) h = (_Float16)(x - (float)h);
  dst[(long)r*dst_ld + dst_off + c] = h;
}

__global__ __launch_bounds__(256) void embgather_k(const float* __restrict__ emb,
    const int* __restrict__ outp, _Float16* __restrict__ dst)
{
  int i = blockIdx.x*256 + threadIdx.x;   // < 2048*512, rows m = t*8+b
  int k = i & 511; int m = i >> 9;
  int t = m >> 3, b = m & 7;
  int tok = outp[b*TT + t];
  dst[i] = (_Float16)emb[(long)tok*HH + k];
}

// epoch-tagged comm words: hi32 = epoch, lo32 = f32 bits. Parity double-buffered:
// buf[par][4096]. prep fills parity 0 with epoch-0 payloads, parity 1 with 0.
__global__ __launch_bounds__(256) void prep_k(const float* __restrict__ b_ih, const float* __restrict__ b_hh,
    const float* __restrict__ ents, float* bsum, unsigned long long* hxe, unsigned long long* ae)
{
  int i = blockIdx.x*256 + threadIdx.x;   // grid 16 -> 4096 threads
  if (i < G4) bsum[i] = b_ih[i] + b_hh[i];
  if (i < BB*HH) {
    int b = i >> 9, j = i & 511;
    float s = 0.f;
    for (int n = 0; n < NE; n++) s += ents[(size_t)((b<<6)+n)*HH + j];
    s *= (1.0f/NE);                 // cx0 = hx0 = mean over ALL NE entities
    hxe[i] = (unsigned long long)__float_as_uint(s);   // parity 0, epoch 0
    hxe[4096 + i] = 0ull;                              // parity 1
    ae[i]  = 0ull;                                     // a0 = 0, epoch 0
    ae[4096 + i] = 0ull;
  }
}

// ---------------- f16 MFMA GEMM: C[M,N](f32) = A[M,K] * B[N,K]^T (+bias) ----------------
// All of M,N,K divisible by 128/32. 128x128 tile, 4 waves each 64x64.
__global__ __launch_bounds__(256) void gemm_k(const _Float16* __restrict__ A, const _Float16* __restrict__ Bm,
    float* __restrict__ C, const float* __restrict__ bias,
    int M, int N, int K, int ldc, int accum)
{
  __shared__ __align__(16) _Float16 At[128][40];
  __shared__ __align__(16) _Float16 Bt[128][40];
  int tid = threadIdx.x;
  int n0 = blockIdx.x * 128, m0 = blockIdx.y * 128;
  int wave = tid >> 6, lane = tid & 63;
  int mw = (wave & 1) << 6, nw = (wave >> 1) << 6;
  int lr = tid >> 2, lc = (tid & 3) << 3;
  const _Float16* Ap0 = A + (long)(m0 + lr)*K + lc;
  const _Float16* Ap1 = Ap0 + (long)64*K;
  const _Float16* Bp0 = Bm + (long)(n0 + lr)*K + lc;
  const _Float16* Bp1 = Bp0 + (long)64*K;
  f4 acc[4][4] = {};
  int rr = lane & 15, kq = (lane >> 4) << 3;
  for (int kt = 0; kt < K; kt += 32) {
    h8 av0 = *(const h8*)(Ap0 + kt);
    h8 av1 = *(const h8*)(Ap1 + kt);
    h8 bv0 = *(const h8*)(Bp0 + kt);
    h8 bv1 = *(const h8*)(Bp1 + kt);
    __syncthreads();
    *(h8*)&At[lr][lc]    = av0;
    *(h8*)&At[64+lr][lc] = av1;
    *(h8*)&Bt[lr][lc]    = bv0;
    *(h8*)&Bt[64+lr][lc] = bv1;
    __syncthreads();
    h8 af[4], bf[4];
    #pragma unroll
    for (int mt=0;mt<4;mt++) af[mt] = *(const h8*)&At[mw + mt*16 + rr][kq];
    #pragma unroll
    for (int nt=0;nt<4;nt++) bf[nt] = *(const h8*)&Bt[nw + nt*16 + rr][kq];
    #pragma unroll
    for (int mt=0;mt<4;mt++)
      #pragma unroll
      for (int nt=0;nt<4;nt++)
        acc[mt][nt] = __builtin_amdgcn_mfma_f32_16x16x32_f16(af[mt], bf[nt], acc[mt][nt], 0, 0, 0);
  }
  // C/D layout: col=lane&15, row=(lane>>4)*4+reg  (dtype-independent on gfx950)
  int cc = lane & 15, rq = (lane >> 4) << 2;
  #pragma unroll
  for (int nt=0;nt<4;nt++) {
    int col = n0 + nw + nt*16 + cc;
    float bv = bias ? bias[col] : 0.f;
    #pragma unroll
    for (int mt=0;mt<4;mt++) {
      int row0 = m0 + mw + mt*16 + rq;
      #pragma unroll
      for (int r=0;r<4;r++) {
        long idx = (long)(row0 + r)*ldc + col;
        float v = acc[mt][nt][r] + bv;
        if (accum) C[idx] += v; else C[idx] = v;
      }
    }
  }
}

// ---------------- persistent LSTM+attention: 32 WGs x 512 threads, wave-specialized ----
// Wave 0: attention for (b_own = wg>>2, hid = wg&3). Polls hx[b_own] only; runs
//   q -> scores -> softmax -> AV -> ae store fully in-wave (no __syncthreads).
// Waves 1..7: gates. Each owns a disjoint k-slice ({3,3,2,2,2,2,2} chunks of 32 per
//   512-half); polls/stages/MFMAs its own slice only -> no cross-wave act dependency.
// Per step only 2 barriers (fing stage + reduce). Comm words (epoch<<32)|f32bits in
// parity double-buffers: store tag et=t+1 into buf[et&1]. Overwrite at t+2 is ordered
// behind all t-readers: cell(t+2) <= S2(t+2) <= gate MFMAs(t+1) <= a-poll(t+1)
// <= ae(t+1) stores <= wave0 full-hx poll(t+1) <= ALL cells(t+1) <= each WG's S2(t+1)
// <= its waves' iter-t bottom (the reads in question). fing parity-buffered likewise.
__global__ __launch_bounds__(512, 1) void lstm_k(
    const float* __restrict__ gates_pre, const _Float16* __restrict__ Wc,
    const _Float16* __restrict__ Wq, const float* __restrict__ Kb, const float* __restrict__ Vb,
    const int* __restrict__ entlens,
    unsigned long long* hxe, unsigned long long* ae,
    _Float16* l_h, _Float16* l_lo)
{
  __shared__ __align__(16) _Float16 wA[64][WSTR];   // 64 gate rows x [a(0:512)|hx(512:1024)]
  __shared__ __align__(16) _Float16 act[8][WSTR];   // [b][a|hx] f16, per-wave-private slices
  __shared__ __align__(16) float hxl[512];          // wave0: own-b hx fp32
  __shared__ __align__(16) float qv[128];           // wave0 only
  __shared__ float sl[64];                          // wave0 only
  __shared__ float fing[2][8][64];                  // parity-buffered gate sums
  __shared__ float cxs[128];                        // cell state [b][jj]

  const int tid = threadIdx.x, wg = blockIdx.x;
  const int lane = tid & 63, w = tid >> 6;
  const int b_own = wg >> 2, hid = wg & 3;
  const int el = entlens[b_own];
  const int gb = w, gn = tid & 63;                             // (b,n) for gpre/fing
  const int gcol = ((gn >> 4) << 9) + (wg << 4) + (gn & 15);   // gpre column
  const int rr = lane & 15, kq = (lane >> 4) << 3;             // MFMA frag addressing
  const int cnt   = (w == 0) ? 0 : (w <= 2) ? 3 : 2;           // k-chunks per half
  const int start = (w == 1) ? 0 : (w == 2) ? 3 : (w << 1);    // chunk start (w>=3: 2w)

  // ---- one-time: weights -> LDS, cx init, initial act (parity 0, no poll) ----
  for (int c = tid; c < 8192; c += 512) {
    int row = c >> 7, k8 = (c & 127) << 3;
    int gr = ((row >> 4) << 9) + (wg << 4) + (row & 15);       // gate*512 + 16wg + jj
    *(h8*)&wA[row][k8] = *(const h8*)(Wc + ((long)gr << 10) + k8);
  }
  if (tid < 128)
    cxs[tid] = __uint_as_float((unsigned)g64load(hxe + ((tid >> 4) << 9) + (wg << 4) + (tid & 15)));
  #pragma unroll
  for (int k = 0; k < 8; k++) {
    act[k][512 + tid] = (_Float16)__uint_as_float((unsigned)g64load(hxe + (k << 9) + tid));
    act[k][tid]       = (_Float16)__uint_as_float((unsigned)g64load(ae  + (k << 9) + tid));
  }
  float gp_reg = gates_pre[((long)gb << 11) + gcol];           // t=0 row = b
  float gpn = 0.f;
  __syncthreads();

  // gates(0): each gate wave, its slices of both halves
  f4 acc[4] = {};
  if (w) {
    #pragma unroll
    for (int sub = 0; sub < 3; sub++) if (sub < cnt) {
      int dh = 512 + ((start + sub) << 5) + kq;
      int da = ((start + sub) << 5) + kq;
      h8 avh = *(const h8*)&act[rr & 7][dh];
      h8 ava = *(const h8*)&act[rr & 7][da];
      #pragma unroll
      for (int nt = 0; nt < 4; nt++) {
        h8 bvh = *(const h8*)&wA[(nt << 4) + rr][dh];
        acc[nt] = __builtin_amdgcn_mfma_f32_16x16x32_f16(avh, bvh, acc[nt], 0, 0, 0);
        h8 bva = *(const h8*)&wA[(nt << 4) + rr][da];
        acc[nt] = __builtin_amdgcn_mfma_f32_16x16x32_f16(ava, bva, acc[nt], 0, 0, 0);
      }
    }
  }

  for (int t = 0; t < TT; t++) {
    float (*fg)[64] = fing[t & 1];
    // ---- S1: stage gpre; S2 after 7-wave partial reduce ----
    fg[gb][gn] = gp_reg;
    __syncthreads();
    if (w && lane < 32) {            // acc rows 0-7 live in lanes 0-31
      int cc = lane & 15, rq = (lane >> 4) << 2;
      #pragma unroll
      for (int nt = 0; nt < 4; nt++)
        #pragma unroll
        for (int r = 0; r < 4; r++)
          atomicAdd(&fg[rq + r][(nt << 4) + cc], acc[nt][r]);
    }
    __syncthreads();
    const int et = t + 1;
    const unsigned uet = (unsigned)et;
    unsigned long long* hb = hxe + ((size_t)(et & 1) << 12);
    unsigned long long* ab = ae  + ((size_t)(et & 1) << 12);
    // ---- LSTM cell: 8b x 16j (waves 0-1) ----
    if (tid < 128) {
      int b = tid >> 4, jj = tid & 15;
      float gi = fg[b][jj], gf = fg[b][16+jj], gg = fg[b][32+jj], go = fg[b][48+jj];
      float c_ = sigf(gf)*cxs[tid] + sigf(gi)*tanhf(gg);
      cxs[tid] = c_;
      float h = sigf(go)*tanhf(c_);
      int j = (wg << 4) + jj;
      g64store(hb + (b << 9) + j,
               ((unsigned long long)uet << 32) | (unsigned long long)__float_as_uint(h));
      _Float16 hh = (_Float16)h;
      long li = ((long)((b << 8) + t)) << 10;
      l_h[li + j]  = hh;
      l_lo[li + j] = (_Float16)(h - (float)hh);
    }
    {
      int tn = (t < TT-1) ? t+1 : TT-1;
      gpn = gates_pre[((long)((tn << 3) + gb) << 11) + gcol];
    }
    asm volatile("" ::: "memory");   // keep hxe stores issued before polls
    if (w == 0) {
      // ================= wave 0: attention, fully in-wave =================
      unsigned long long vq8[8];
      #pragma unroll
      for (int k = 0; k < 8; k++) vq8[k] = g64load(hb + (b_own << 9) + (k << 6) + lane);
      for (;;) {
        bool ok = true;
        #pragma unroll
        for (int k = 0; k < 8; k++) if ((unsigned)(vq8[k] >> 32) < uet) ok = false;
        if (ok) break;
        __builtin_amdgcn_s_sleep(1);
        #pragma unroll
        for (int k = 0; k < 8; k++)
          if ((unsigned)(vq8[k] >> 32) < uet) vq8[k] = g64load(hb + (b_own << 9) + (k << 6) + lane);
      }
      #pragma unroll
      for (int k = 0; k < 8; k++) hxl[(k << 6) + lane] = __uint_as_float((unsigned)vq8[k]);
      // q: lane computes dims (lane, 64+lane) of head hid; fp32 hx, f16 W
      const _Float16* wq0 = Wq + (((long)((hid << 7) + lane)) << 9);
      const _Float16* wq1 = wq0 + (64 << 9);
      float s0 = 0.f, s1 = 0.f;
      for (int k8 = 0; k8 < 64; k8++) {
        h8 wa = *(const h8*)(wq0 + (k8 << 3));
        h8 wb = *(const h8*)(wq1 + (k8 << 3));
        const float* hp = &hxl[k8 << 3];
        #pragma unroll
        for (int j2 = 0; j2 < 8; j2++) { float hv = hp[j2]; s0 += (float)wa[j2]*hv; s1 += (float)wb[j2]*hv; }
      }
      qv[lane] = s0; qv[64 + lane] = s1;
      // scores + softmax (lane = entity)
      const f4* kp4 = (const f4*)(Kb + (((long)((b_own << 6) + lane)) << 9) + (hid << 7));
      float s = 0.f;
      #pragma unroll 8
      for (int d4 = 0; d4 < 32; d4++) {
        f4 kv = kp4[d4]; f4 qq = *(const f4*)&qv[d4 << 2];
        s += qq[0]*kv[0] + qq[1]*kv[1] + qq[2]*kv[2] + qq[3]*kv[3];
      }
      s *= SCALE;
      if (lane > el) s = -1e30f;
      float mx = s;
      #pragma unroll
      for (int off = 32; off > 0; off >>= 1) mx = fmaxf(mx, __shfl_xor(mx, off));
      float e = __expf(s - mx), sm = e;
      #pragma unroll
      for (int off = 32; off > 0; off >>= 1) sm += __shfl_xor(sm, off);
      sl[lane] = e / sm;
      // AV: lane computes dims (lane, 64+lane)
      const float* vp0 = Vb + (((long)(b_own << 6)) << 9) + (hid << 7) + lane;
      float a0 = 0.f, a1 = 0.f;
      #pragma unroll 8
      for (int n = 0; n < 64; n++) {
        float p = sl[n];
        a0 += p * vp0[(long)n << 9];
        a1 += p * vp0[((long)n << 9) + 64];
      }
      long li = (((long)((b_own << 8) + t)) << 10) + 512 + (hid << 7);
      _Float16 h0 = (_Float16)a0, h1 = (_Float16)a1;
      l_h[li + lane]       = h0;
      l_h[li + 64 + lane]  = h1;
      l_lo[li + lane]      = (_Float16)(a0 - (float)h0);
      l_lo[li + 64 + lane] = (_Float16)(a1 - (float)h1);
      g64store(ab + (b_own << 9) + (hid << 7) + lane,
               ((unsigned long long)uet << 32) | (unsigned long long)__float_as_uint(a0));
      g64store(ab + (b_own << 9) + (hid << 7) + 64 + lane,
               ((unsigned long long)uet << 32) | (unsigned long long)__float_as_uint(a1));
    } else {
      // ================= gate waves: hx-half (own slice) =================
      #pragma unroll
      for (int nt = 0; nt < 4; nt++) { f4 z = {}; acc[nt] = z; }
      unsigned long long vh[12];
      #pragma unroll
      for (int i = 0; i < 12; i++) if (i < (cnt << 2)) {
        int sub = i >> 2, q = i & 3;
        vh[i] = g64load(hb + (((q << 1) + (lane >> 5)) << 9) + ((start + sub) << 5) + (lane & 31));
      }
      for (;;) {
        bool ok = true;
        #pragma unroll
        for (int i = 0; i < 12; i++) if (i < (cnt << 2) && (unsigned)(vh[i] >> 32) < uet) ok = false;
        if (ok) break;
        __builtin_amdgcn_s_sleep(1);
        #pragma unroll
        for (int i = 0; i < 12; i++) if (i < (cnt << 2) && (unsigned)(vh[i] >> 32) < uet) {
          int sub = i >> 2, q = i & 3;
          vh[i] = g64load(hb + (((q << 1) + (lane >> 5)) << 9) + ((start + sub) << 5) + (lane & 31));
        }
      }
      #pragma unroll
      for (int i = 0; i < 12; i++) if (i < (cnt << 2)) {
        int sub = i >> 2, q = i & 3;
        act[(q << 1) + (lane >> 5)][512 + ((start + sub) << 5) + (lane & 31)] =
            (_Float16)__uint_as_float((unsigned)vh[i]);
      }
      #pragma unroll
      for (int sub = 0; sub < 3; sub++) if (sub < cnt) {
        int d = 512 + ((start + sub) << 5) + kq;
        h8 av = *(const h8*)&act[rr & 7][d];
        #pragma unroll
        for (int nt = 0; nt < 4; nt++) {
          h8 bv = *(const h8*)&wA[(nt << 4) + rr][d];
          acc[nt] = __builtin_amdgcn_mfma_f32_16x16x32_f16(av, bv, acc[nt], 0, 0, 0);
        }
      }
    }
    if (t == TT - 1) break;
    if (w) {
      // ================= gate waves: a-half (own slice) =================
      unsigned long long va[12];
      #pragma unroll
      for (int i = 0; i < 12; i++) if (i < (cnt << 2)) {
        int sub = i >> 2, q = i & 3;
        va[i] = g64load(ab + (((q << 1) + (lane >> 5)) << 9) + ((start + sub) << 5) + (lane & 31));
      }
      for (;;) {
        bool ok = true;
        #pragma unroll
        for (int i = 0; i < 12; i++) if (i < (cnt << 2) && (unsigned)(va[i] >> 32) < uet) ok = false;
        if (ok) break;
        __builtin_amdgcn_s_sleep(1);
        #pragma unroll
        for (int i = 0; i < 12; i++) if (i < (cnt << 2) && (unsigned)(va[i] >> 32) < uet) {
          int sub = i >> 2, q = i & 3;
          va[i] = g64load(ab + (((q << 1) + (lane >> 5)) << 9) + ((start + sub) << 5) + (lane & 31));
        }
      }
      #pragma unroll
      for (int i = 0; i < 12; i++) if (i < (cnt << 2)) {
        int sub = i >> 2, q = i & 3;
        act[(q << 1) + (lane >> 5)][((start + sub) << 5) + (lane & 31)] =
            (_Float16)__uint_as_float((unsigned)va[i]);
      }
      #pragma unroll
      for (int sub = 0; sub < 3; sub++) if (sub < cnt) {
        int d = ((start + sub) << 5) + kq;
        h8 av = *(const h8*)&act[rr & 7][d];
        #pragma unroll
        for (int nt = 0; nt < 4; nt++) {
          h8 bv = *(const h8*)&wA[(nt << 4) + rr][d];
          acc[nt] = __builtin_amdgcn_mfma_f32_16x16x32_f16(av, bv, acc[nt], 0, 0, 0);
        }
      }
    }
    gp_reg = gpn;
  }
}

// ---------------- online softmax stats over V + sigmoid switch gate ----------------
__global__ __launch_bounds__(256) void stats_k(const float* __restrict__ out0,
    const _Float16* __restrict__ l_h, const float* __restrict__ swW, const float* __restrict__ swb,
    float* rowmax, float* rowsum, float* sgate)
{
  int m = blockIdx.x, tid = threadIdx.x;
  const float* row = out0 + (long)m*RS;
  float mx = -1e30f, sm = 0.f;
  for (int c = tid; c < VOCAB; c += 256) {
    float x = row[c];
    float nm = fmaxf(mx, x);
    sm = sm*__expf(mx-nm) + __expf(x-nm);
    mx = nm;
  }
  float sd = 0.f;
  const _Float16* lr_ = l_h + ((long)m << 10);
  for (int k = tid; k < 1024; k += 256) sd += (float)lr_[k] * swW[k];
  #pragma unroll
  for (int off=32; off>0; off>>=1) {
    float omx = __shfl_xor(mx, off), osm = __shfl_xor(sm, off);
    float nm = fmaxf(mx, omx);
    sm = sm*__expf(mx-nm) + osm*__expf(omx-nm);
    mx = nm;
    sd += __shfl_xor(sd, off);
  }
  __shared__ float smx[4], ssm[4], ssd[4];
  int wv = tid >> 6;
  if ((tid & 63) == 0) { smx[wv]=mx; ssm[wv]=sm; ssd[wv]=sd; }
  __syncthreads();
  if (tid == 0) {
    float M = smx[0], S = ssm[0], D = ssd[0];
    for (int w2=1;w2<4;w2++) {
      float nm = fmaxf(M, smx[w2]);
      S = S*__expf(M-nm) + ssm[w2]*__expf(smx[w2]-nm);
      M = nm; D += ssd[w2];
    }
    rowmax[m] = M; rowsum[m] = S;
    sgate[m] = 1.f/(1.f + __expf(-(D + swb[0])));
  }
}

// ---------------- finalize: log(softmax*s + 1e-6) over V, pointer softmax z over NE ----------------
__global__ __launch_bounds__(256) void fin_k(float* __restrict__ out,
    const float* __restrict__ dec, const float* __restrict__ ents, const int* __restrict__ entlens,
    const float* __restrict__ rowmax, const float* __restrict__ rowsum, const float* __restrict__ sgate)
{
  int m = blockIdx.x, tid = threadIdx.x;
  int b = m >> 8;
  __shared__ float dl[512];
  for (int i = tid; i < 512; i += 256) dl[i] = dec[((long)m<<9) + i];
  __syncthreads();
  float s = sgate[m];
  if (tid < 64) {
    int n = tid;
    const float* ep = ents + (((long)((b<<6)+n)) << 9);
    float uq = 0.f;
    for (int k=0;k<512;k+=4)
      uq += dl[k]*ep[k] + dl[k+1]*ep[k+1] + dl[k+2]*ep[k+2] + dl[k+3]*ep[k+3];
    if (n > entlens[b]) uq = -1e30f;
    float mx = uq;
    #pragma unroll
    for (int off=32; off>0; off>>=1) mx = fmaxf(mx, __shfl_xor(mx, off));
    float e = __expf(uq - mx);
    float sum = e;
    #pragma unroll
    for (int off=32; off>0; off>>=1) sum += __shfl_xor(sum, off);
    float z = (e/sum) * (1.f - s);
    out[(long)m*RS + VOCAB + n] = __logf(z + 1e-6f);
    out[(long)MROWS*RS + ((long)m<<6) + n] = z;     // output 1
  }
  float mx = rowmax[m], inv = 1.f/rowsum[m];
  for (int c = tid; c < VOCAB; c += 256) {
    long idx = (long)m*RS + c;
    float x = out[idx];
    out[idx] = __logf(__expf(x - mx)*inv*s + 1e-6f);
  }
}

// ---------------- launch ----------------
extern "C" void kernel_launch(void* const* d_in, const int* in_sizes, int n_in,
                              void* d_out, int out_size, void* d_ws, size_t ws_size,
                              hipStream_t stream)
{
  const int*   outp    = (const int*)d_in[0];
  const float* ents    = (const float*)d_in[1];
  const int*   entlens = (const int*)d_in[2];
  const float* emb     = (const float*)d_in[3];
  const float* W_ih    = (const float*)d_in[4];
  const float* W_hh    = (const float*)d_in[5];
  const float* b_ih    = (const float*)d_in[6];
  const float* b_hh    = (const float*)d_in[7];
  const float* Wq      = (const float*)d_in[8];
  const float* Wk      = (const float*)d_in[9];
  const float* Wv      = (const float*)d_in[10];
  const float* out_W   = (const float*)d_in[11];
  const float* out_b   = (const float*)d_in[12];
  const float* sw_W    = (const float*)d_in[13];
  const float* sw_b    = (const float*)d_in[14];
  const float* mattn_W = (const float*)d_in[15];
  const float* mattn_b = (const float*)d_in[16];
  float* out = (float*)d_out;
  (void)in_sizes; (void)n_in; (void)out_size; (void)ws_size;

  char* w = (char*)d_ws;
  size_t off = 0;
  auto alloc = [&](size_t bytes) -> char* {
    char* p = w + off; off += bytes; off = (off + 255) & ~(size_t)255; return p;
  };
  _Float16* outW_h = (_Float16*)alloc((size_t)VOCAB*1024*2);
  _Float16* l_h    = (_Float16*)alloc((size_t)MROWS*1024*2);
  _Float16* l_lo   = (_Float16*)alloc((size_t)MROWS*1024*2);
  float*    gpre   = (float*)alloc((size_t)MROWS*2048*4);
  _Float16* Wc_h   = (_Float16*)alloc((size_t)2048*1024*2);
  _Float16* Wihk_h = (_Float16*)alloc((size_t)2048*512*2);
  _Float16* emb_h  = (_Float16*)alloc((size_t)2048*512*2);
  _Float16* ents_h = (_Float16*)alloc((size_t)512*512*2);
  _Float16* Wk_h   = (_Float16*)alloc((size_t)512*512*2);
  _Float16* Wv_h   = (_Float16*)alloc((size_t)512*512*2);
  _Float16* Wq_h   = (_Float16*)alloc((size_t)512*512*2);
  _Float16* mat_h  = (_Float16*)alloc((size_t)512*1024*2);
  _Float16* mat_lo = (_Float16*)alloc((size_t)512*1024*2);
  float*    Kb     = (float*)alloc((size_t)512*512*4);
  float*    Vb     = (float*)alloc((size_t)512*512*4);
  float*    dec    = (float*)alloc((size_t)MROWS*512*4);
  float*    bsum   = (float*)alloc(2048*4);
  unsigned long long* hxe = (unsigned long long*)alloc((size_t)2*4096*8);  // parity x epoch|f32
  unsigned long long* ae  = (unsigned long long*)alloc((size_t)2*4096*8);
  float*    rmax   = (float*)alloc(2048*4);
  float*    rsum   = (float*)alloc(2048*4);
  float*    sg     = (float*)alloc(2048*4);

  auto cast = [&](const float* s, _Float16* d, int total, int sld, int soff, int dld, int doff, int cs, int lo) {
    cast_k<<<(total+255)/256, 256, 0, stream>>>(s, d, total, sld, soff, dld, doff, cs, lo);
  };
  cast(out_W,   outW_h, VOCAB*1024, 1024, 0,   1024, 0,   10, 0);
  cast(W_ih,    Wihk_h, 2048*512,   1024, 512, 512,  0,   9,  0);
  cast(W_ih,    Wc_h,   2048*512,   1024, 0,   1024, 0,   9,  0);
  cast(W_hh,    Wc_h,   2048*512,   512,  0,   1024, 512, 9,  0);
  cast(Wq,      Wq_h,   512*512,    512,  0,   512,  0,   9,  0);
  cast(Wk,      Wk_h,   512*512,    512,  0,   512,  0,   9,  0);
  cast(Wv,      Wv_h,   512*512,    512,  0,   512,  0,   9,  0);
  cast(mattn_W, mat_h,  512*1024,   1024, 0,   1024, 0,   10, 0);
  cast(mattn_W, mat_lo, 512*1024,   1024, 0,   1024, 0,   10, 1);
  cast(ents,    ents_h, 512*512,    512,  0,   512,  0,   9,  0);

  embgather_k<<<4096, 256, 0, stream>>>(emb, outp, emb_h);
  prep_k<<<16, 256, 0, stream>>>(b_ih, b_hh, ents, bsum, hxe, ae);

  gemm_k<<<dim3(4,4),   256, 0, stream>>>(ents_h, Wk_h,   Kb,   nullptr, 512,  512,   512,  512,  0);
  gemm_k<<<dim3(4,4),   256, 0, stream>>>(ents_h, Wv_h,   Vb,   nullptr, 512,  512,   512,  512,  0);
  gemm_k<<<dim3(16,16), 256, 0, stream>>>(emb_h,  Wihk_h, gpre, bsum,    2048, 2048,  512,  2048, 0);

  lstm_k<<<LWG, 512, 0, stream>>>(gpre, Wc_h, Wq_h, Kb, Vb, entlens,
                                  hxe, ae, l_h, l_lo);

  gemm_k<<<dim3(4,16),   256, 0, stream>>>(l_h,  mat_h,  dec, mattn_b, 2048, 512,   1024, 512, 0);
  gemm_k<<<dim3(4,16),   256, 0, stream>>>(l_lo, mat_h,  dec, nullptr, 2048, 512,   1024, 512, 1);
  gemm_k<<<dim3(4,16),   256, 0, stream>>>(l_h,  mat_lo, dec, nullptr, 2048, 512,   1024, 512, 1);
  gemm_k<<<dim3(250,16), 256, 0, stream>>>(l_h,  outW_h, out, out_b,   2048, 32000, 1024, RS,  0);

  stats_k<<<2048, 256, 0, stream>>>(out, l_h, sw_W, sw_b, rmax, rsum, sg);
  fin_k<<<2048, 256, 0, stream>>>(out, dec, ents, entlens, rmax, rsum, sg);
}

// Round 5
// 2212.058 us; speedup vs baseline: 3.0912x; 3.0912x over previous
//
#include <hip/hip_runtime.h>
#include <cstdint>

#define TT 256
#define BB 8
#define NE 64
#define HH 512
#define VOCAB 32000
#define G4 2048
#define RS 32064          // out0 row stride (V + NE)
#define MROWS 2048        // B*T
#define SCALE 0.044194173824159216f  // 1/sqrt(512)

typedef _Float16 h2 __attribute__((ext_vector_type(2)));
typedef _Float16 h8 __attribute__((ext_vector_type(8)));
typedef float f4 __attribute__((ext_vector_type(4)));
typedef unsigned long long u64;

__device__ inline float sigf(float x){ return 1.f/(1.f+__expf(-x)); }

// agent-scope 64-bit payload words: hi32 = epoch, lo32 = f32 bits (single-copy atomic)
__device__ inline u64 g64load(const u64* p){
  return __hip_atomic_load((u64*)p, __ATOMIC_RELAXED, __HIP_MEMORY_SCOPE_AGENT);
}
__device__ inline void g64store(u64* p, u64 v){
  __hip_atomic_store(p, v, __ATOMIC_RELAXED, __HIP_MEMORY_SCOPE_AGENT);
}

// ---------------- casts (f32 -> f16, hi or lo residual, optional scale/transpose) ----------------
__global__ __launch_bounds__(256) void cast_k(const float* __restrict__ src, _Float16* __restrict__ dst,
    int total, int src_ld, int src_off, int dst_ld, int dst_off, int cshift, int lo, float mul, int tr)
{
  int i = blockIdx.x*256 + threadIdx.x;
  if (i >= total) return;
  int c = i & ((1<<cshift)-1);
  int r = i >> cshift;
  float x = src[(long)r*src_ld + src_off + c] * mul;
  _Float16 h = (_Float16)x;
  if (lo) h = (_Float16)(x - (float)h);
  if (tr) dst[(long)c*dst_ld + dst_off + r] = h;
  else    dst[(long)r*dst_ld + dst_off + c] = h;
}

__global__ __launch_bounds__(256) void embgather_k(const float* __restrict__ emb,
    const int* __restrict__ outp, _Float16* __restrict__ dst)
{
  int i = blockIdx.x*256 + threadIdx.x;   // < 2048*512, rows m = t*8+b
  int k = i & 511; int m = i >> 9;
  int t = m >> 3, b = m & 7;
  int tok = outp[b*TT + t];
  dst[i] = (_Float16)emb[(long)tok*HH + k];
}

// prep: bias sum; hx(-1) = mean(ents) epoch-0 payload words; S buffer zero
__global__ __launch_bounds__(256) void prep_k(const float* __restrict__ b_ih, const float* __restrict__ b_hh,
    const float* __restrict__ ents, float* bsum, u64* hxe, u64* Se)
{
  int i = blockIdx.x*256 + threadIdx.x;   // grid 16 -> 4096 threads
  if (i < G4) bsum[i] = b_ih[i] + b_hh[i];
  if (i < BB*HH) {
    int b = i >> 9, j = i & 511;
    float s = 0.f;
    for (int n = 0; n < NE; n++) s += ents[(size_t)((b<<6)+n)*HH + j];
    s *= (1.0f/NE);
    hxe[i] = (u64)__float_as_uint(s);     // epoch 0
  }
  if (i < BB*256) Se[i] = 0ull;
}

// build block-diagonal-expanded V (f16), both row layouts:
// VblkS[(b*256+he)][d] and VblkT[b][d][he], val = (he head == d head) ? V[b][e][d] : 0
__global__ __launch_bounds__(256) void vblk_k(const float* __restrict__ Vb,
    _Float16* __restrict__ VblkS, _Float16* __restrict__ VblkT)
{
  int i = blockIdx.x*256 + threadIdx.x;   // < 8*512*256 = 1,048,576
  int he = i & 255, d = (i >> 8) & 511, b = i >> 17;
  _Float16 v = (_Float16)0.f;
  if ((he >> 6) == (d >> 7)) v = (_Float16)Vb[(((long)((b<<6)|(he&63)))<<9) + d];
  VblkT[(((long)((b<<9)|d))<<8) + he] = v;
  VblkS[(((long)((b<<8)|he))<<9) + d] = v;
}

// ---------------- f16 MFMA GEMM: C[M,N](f32) = A[M,K] * B[N,K]^T (+bias) ----------------
// lda/ldb/ldc explicit; optional batch via blockIdx.z with element strides sA/sB/sC.
__global__ __launch_bounds__(256) void gemm_k(const _Float16* __restrict__ A, const _Float16* __restrict__ Bm,
    float* __restrict__ C, const float* __restrict__ bias,
    int M, int N, int K, int lda, int ldb, int ldc, int accum, long sA, long sB, long sC)
{
  __shared__ __align__(16) _Float16 At[128][40];
  __shared__ __align__(16) _Float16 Bt[128][40];
  int z = blockIdx.z;
  A  += (long)z * sA;  Bm += (long)z * sB;  C += (long)z * sC;
  int tid = threadIdx.x;
  int n0 = blockIdx.x * 128, m0 = blockIdx.y * 128;
  int wave = tid >> 6, lane = tid & 63;
  int mw = (wave & 1) << 6, nw = (wave >> 1) << 6;
  int lr = tid >> 2, lc = (tid & 3) << 3;
  const _Float16* Ap0 = A + (long)(m0 + lr)*lda + lc;
  const _Float16* Ap1 = Ap0 + (long)64*lda;
  const _Float16* Bp0 = Bm + (long)(n0 + lr)*ldb + lc;
  const _Float16* Bp1 = Bp0 + (long)64*ldb;
  f4 acc[4][4] = {};
  int rr = lane & 15, kq = (lane >> 4) << 3;
  for (int kt = 0; kt < K; kt += 32) {
    h8 av0 = *(const h8*)(Ap0 + kt);
    h8 av1 = *(const h8*)(Ap1 + kt);
    h8 bv0 = *(const h8*)(Bp0 + kt);
    h8 bv1 = *(const h8*)(Bp1 + kt);
    __syncthreads();
    *(h8*)&At[lr][lc]    = av0;
    *(h8*)&At[64+lr][lc] = av1;
    *(h8*)&Bt[lr][lc]    = bv0;
    *(h8*)&Bt[64+lr][lc] = bv1;
    __syncthreads();
    h8 af[4], bf[4];
    #pragma unroll
    for (int mt=0;mt<4;mt++) af[mt] = *(const h8*)&At[mw + mt*16 + rr][kq];
    #pragma unroll
    for (int nt=0;nt<4;nt++) bf[nt] = *(const h8*)&Bt[nw + nt*16 + rr][kq];
    #pragma unroll
    for (int mt=0;mt<4;mt++)
      #pragma unroll
      for (int nt=0;nt<4;nt++)
        acc[mt][nt] = __builtin_amdgcn_mfma_f32_16x16x32_f16(af[mt], bf[nt], acc[mt][nt], 0, 0, 0);
  }
  int cc = lane & 15, rq = (lane >> 4) << 2;
  #pragma unroll
  for (int nt=0;nt<4;nt++) {
    int col = n0 + nw + nt*16 + cc;
    float bv = bias ? bias[col] : 0.f;
    #pragma unroll
    for (int mt=0;mt<4;mt++) {
      int row0 = m0 + mw + mt*16 + rq;
      #pragma unroll
      for (int r=0;r<4;r++) {
        long idx = (long)(row0 + r)*ldc + col;
        float v = acc[mt][nt][r] + bv;
        if (accum) C[idx] += v; else C[idx] = v;
      }
    }
  }
}

// ---------------- batch-local persistent RNN: 8 groups x 32 WGs (1 WG/CU) ----------------
// Group = batch b (wg>>5). WG (wgl = wg&31) owns 16 hidden units (64 gate rows, f16
// weights in LDS) and 8 score rows. Per step: exchange hx (512 words) then S (256
// words), both batch-local epoch-tagged payload words. Attention is OUT of the loop:
//   gates_a = WV @ p   (WV = W_ih_a @ Vblk precomputed)
//   S       = hx @ M   (M  = scale * K_h @ Wq_h^T precomputed)
// a itself is reconstructed post-loop as A = P @ Vblk (batched GEMM).
// Single-buffer safety: hxe word overwrite (epoch it+2) waits on owner's S-poll(it+2)
// <- every WG's S-store(it+1) <- its hx-poll(it+1) complete (the read in question);
// symmetric for Se. it=0 runs a dummy S-round so init-stage reads are interlocked.
__global__ __launch_bounds__(512, 1) void rnn_k(
    const float* __restrict__ gates_pre, const _Float16* __restrict__ Whh16,
    const float* __restrict__ Mh, const float* __restrict__ WVall,
    const int* __restrict__ entlens,
    u64* hxe, u64* Se, _Float16* Pg, _Float16* l_h, _Float16* l_lo)
{
  __shared__ __align__(16) _Float16 Wl[64][528];   // 67.6 KB  gate-row weights (hx part)
  __shared__ __align__(16) float    Ml[8][516];    // 16.5 KB  score rows
  __shared__ __align__(16) _Float16 WVl[64][264];  // 33.8 KB  gate-row weights (p part)
  __shared__ __align__(16) float    hxs[512];      // staged hx f32
  __shared__ __align__(16) _Float16 hxh[512];      // staged hx f16
  __shared__ __align__(16) _Float16 ph[256];       // p f16 (wave0)
  __shared__ float gsum[64];                       // hh-matvec row sums
  __shared__ float gpl[64];                        // gpre prefetch

  const int tid = threadIdx.x, wg = blockIdx.x;
  const int b = wg >> 5, wgl = wg & 31, u_off = wgl << 4;
  const int lane = tid & 63, wv = tid >> 6;
  const int el = entlens[b];
  const int h_own = wgl >> 3, e_base = (wgl & 7) << 3;  // score rows [8wgl,8wgl+8)
  u64* hxb = hxe + ((long)b << 9);
  u64* Sb  = Se  + ((long)b << 8);

  // ---- one-time: weights -> LDS ----
  for (int i = tid; i < 64*64; i += 512) {          // Whh rows, h8 chunks
    int r = i >> 6, c8 = (i & 63) << 3;
    int grow = ((r >> 4) << 9) + u_off + (r & 15);  // gate*512 + 16wgl + u
    *(h8*)&Wl[r][c8] = *(const h8*)(Whh16 + ((long)grow << 9) + c8);
  }
  for (int i = tid; i < 8*128; i += 512) {          // M rows (f32, f4 chunks)
    int r = i >> 7, c4 = (i & 127) << 2;
    const float* src = Mh + ((long)h_own << 18) + (((long)((b << 6) + e_base + r)) << 9) + c4;
    *(f4*)&Ml[r][c4] = *(const f4*)src;
  }
  for (int i = tid; i < 64*256; i += 512) {         // WV rows (f32 -> f16)
    int r = i >> 8, c = i & 255;
    int grow = ((r >> 4) << 9) + u_off + (r & 15);
    WVl[r][c] = (_Float16)WVall[((long)grow << 11) + (b << 8) + c];
  }
  // ---- stage hx(-1) (epoch 0 from prep, same stream: plain load) ----
  if (tid < 256) {
    u64 w0 = g64load(hxb + 2*tid), w1 = g64load(hxb + 2*tid + 1);
    float f0 = __uint_as_float((unsigned)w0), f1 = __uint_as_float((unsigned)w1);
    hxs[2*tid] = f0; hxs[2*tid+1] = f1;
    hxh[2*tid] = (_Float16)f0; hxh[2*tid+1] = (_Float16)f1;
  }
  __syncthreads();
  float cx = 0.f;
  if (wv == 0 && lane < 16) cx = hxs[u_off + lane];   // cx0 = hx0

  for (int it = 0; it < TT; it++) {
    const unsigned set = (unsigned)(it + 1);
    // ---- A: score row (wave wv), S = hxs . Ml[wv], tag it+1 (dummy at it=0 = interlock) ----
    {
      float sp = 0.f;
      const float* mr = &Ml[wv][lane << 3];
      const float* hp = &hxs[lane << 3];
      #pragma unroll
      for (int j = 0; j < 8; j++) sp += hp[j] * mr[j];
      #pragma unroll
      for (int off = 32; off; off >>= 1) sp += __shfl_xor(sp, off);
      if (lane == 0)
        g64store(Sb + (h_own << 6) + e_base + wv,
                 ((u64)set << 32) | (u64)__float_as_uint(sp));
    }
    if (tid < 64) {   // gpre prefetch (wave0 lanes)
      int col = ((tid >> 4) << 9) + u_off + (tid & 15);
      gpl[tid] = gates_pre[((long)((it << 3) + b) << 11) + col];
    }
    // ---- B: hh matvec, gates_hh[r] = Whh[r] . hxh ----
    {
      int r = tid >> 3, sl = tid & 7;
      float s = 0.f;
      #pragma unroll
      for (int c = 0; c < 8; c++) {
        int k = (sl << 6) + (c << 3);
        union { h8 v; h2 p[4]; } a_, w_;
        a_.v = *(const h8*)&hxh[k];
        w_.v = *(const h8*)&Wl[r][k];
        #pragma unroll
        for (int p = 0; p < 4; p++) s = __builtin_amdgcn_fdot2(a_.p[p], w_.p[p], s, false);
      }
      s += __shfl_xor(s, 1); s += __shfl_xor(s, 2); s += __shfl_xor(s, 4);
      if (sl == 0) gsum[r] = s;
    }
    __syncthreads();   // C: gsum/gpl ready; hxs free to overwrite at F
    // ---- D+E (wave0): poll S -> softmax -> WVp -> cell -> hx store ----
    if (wv == 0) {
      u64 sv[4];
      #pragma unroll
      for (int j = 0; j < 4; j++) sv[j] = g64load(Sb + (j << 6) + lane);
      for (;;) {
        bool ok = true;
        #pragma unroll
        for (int j = 0; j < 4; j++) if ((unsigned)(sv[j] >> 32) < set) ok = false;
        if (ok) break;
        __builtin_amdgcn_s_sleep(1);
        #pragma unroll
        for (int j = 0; j < 4; j++)
          if ((unsigned)(sv[j] >> 32) < set) sv[j] = g64load(Sb + (j << 6) + lane);
      }
      float wvp = 0.f;
      if (it > 0) {
        #pragma unroll
        for (int j = 0; j < 4; j++) {       // softmax head j (lane = entity)
          float x = __uint_as_float((unsigned)sv[j]);
          if (lane > el) x = -1e30f;
          float mx = x;
          #pragma unroll
          for (int off = 32; off; off >>= 1) mx = fmaxf(mx, __shfl_xor(mx, off));
          float e = __expf(x - mx), sm = e;
          #pragma unroll
          for (int off = 32; off; off >>= 1) sm += __shfl_xor(sm, off);
          float p = e / sm;
          _Float16 p16 = (_Float16)p;
          ph[(j << 6) + lane] = p16;
          Pg[((long)((b << 8) + (it - 1)) << 8) + (j << 6) + lane] = p16;
        }
        float s = 0.f;                       // WVp: lane = gate row
        #pragma unroll
        for (int c = 0; c < 32; c++) {
          union { h8 v; h2 p[4]; } pv, wv_;
          pv.v  = *(const h8*)&ph[c << 3];
          wv_.v = *(const h8*)&WVl[lane][c << 3];
          #pragma unroll
          for (int p2 = 0; p2 < 4; p2++) s = __builtin_amdgcn_fdot2(pv.p[p2], wv_.p[p2], s, false);
        }
        wvp = s;
      }
      float gv = gpl[lane] + gsum[lane] + wvp;
      float gi = __shfl(gv, lane & 15);
      float gf = __shfl(gv, 16 + (lane & 15));
      float gg = __shfl(gv, 32 + (lane & 15));
      float go = __shfl(gv, 48 + (lane & 15));
      if (lane < 16) {
        float c_ = sigf(gf)*cx + sigf(gi)*tanhf(gg);
        cx = c_;
        float h = sigf(go)*tanhf(c_);
        int j = u_off + lane;
        g64store(hxb + j, ((u64)set << 32) | (u64)__float_as_uint(h));
        _Float16 hh_ = (_Float16)h;
        long li = ((long)((b << 8) + it)) << 10;
        l_h[li + j]  = hh_;
        l_lo[li + j] = (_Float16)(h - (float)hh_);
      }
    }
    // ---- F: poll hx(it) epoch it+1, restage ----
    if (tid < 256) {
      u64 w0 = g64load(hxb + 2*tid), w1 = g64load(hxb + 2*tid + 1);
      while ((unsigned)(w0 >> 32) < set) { __builtin_amdgcn_s_sleep(1); w0 = g64load(hxb + 2*tid); }
      while ((unsigned)(w1 >> 32) < set) { __builtin_amdgcn_s_sleep(1); w1 = g64load(hxb + 2*tid + 1); }
      float f0 = __uint_as_float((unsigned)w0), f1 = __uint_as_float((unsigned)w1);
      hxs[2*tid] = f0; hxs[2*tid+1] = f1;
      hxh[2*tid] = (_Float16)f0; hxh[2*tid+1] = (_Float16)f1;
    }
    __syncthreads();   // G
  }
  // ---- epilogue: p(255) from hx(255), tag 257 ----
  {
    float sp = 0.f;
    const float* mr = &Ml[wv][lane << 3];
    const float* hp = &hxs[lane << 3];
    #pragma unroll
    for (int j = 0; j < 8; j++) sp += hp[j] * mr[j];
    #pragma unroll
    for (int off = 32; off; off >>= 1) sp += __shfl_xor(sp, off);
    if (lane == 0)
      g64store(Sb + (h_own << 6) + e_base + wv, ((u64)257u << 32) | (u64)__float_as_uint(sp));
    if (wv == 0) {
      u64 sv[4];
      #pragma unroll
      for (int j = 0; j < 4; j++) sv[j] = g64load(Sb + (j << 6) + lane);
      for (;;) {
        bool ok = true;
        #pragma unroll
        for (int j = 0; j < 4; j++) if ((unsigned)(sv[j] >> 32) < 257u) ok = false;
        if (ok) break;
        __builtin_amdgcn_s_sleep(1);
        #pragma unroll
        for (int j = 0; j < 4; j++)
          if ((unsigned)(sv[j] >> 32) < 257u) sv[j] = g64load(Sb + (j << 6) + lane);
      }
      #pragma unroll
      for (int j = 0; j < 4; j++) {
        float x = __uint_as_float((unsigned)sv[j]);
        if (lane > el) x = -1e30f;
        float mx = x;
        #pragma unroll
        for (int off = 32; off; off >>= 1) mx = fmaxf(mx, __shfl_xor(mx, off));
        float e = __expf(x - mx), sm = e;
        #pragma unroll
        for (int off = 32; off; off >>= 1) sm += __shfl_xor(sm, off);
        Pg[((long)((b << 8) + 255) << 8) + (j << 6) + lane] = (_Float16)(e / sm);
      }
    }
  }
}

// ---------------- online softmax stats over V + sigmoid switch gate ----------------
__global__ __launch_bounds__(256) void stats_k(const float* __restrict__ out0,
    const _Float16* __restrict__ l_h, const float* __restrict__ swW, const float* __restrict__ swb,
    float* rowmax, float* rowsum, float* sgate)
{
  int m = blockIdx.x, tid = threadIdx.x;
  const float* row = out0 + (long)m*RS;
  float mx = -1e30f, sm = 0.f;
  for (int c = tid; c < VOCAB; c += 256) {
    float x = row[c];
    float nm = fmaxf(mx, x);
    sm = sm*__expf(mx-nm) + __expf(x-nm);
    mx = nm;
  }
  float sd = 0.f;
  const _Float16* lr_ = l_h + ((long)m << 10);
  for (int k = tid; k < 1024; k += 256) sd += (float)lr_[k] * swW[k];
  #pragma unroll
  for (int off=32; off>0; off>>=1) {
    float omx = __shfl_xor(mx, off), osm = __shfl_xor(sm, off);
    float nm = fmaxf(mx, omx);
    sm = sm*__expf(mx-nm) + osm*__expf(omx-nm);
    mx = nm;
    sd += __shfl_xor(sd, off);
  }
  __shared__ float smx[4], ssm[4], ssd[4];
  int wv = tid >> 6;
  if ((tid & 63) == 0) { smx[wv]=mx; ssm[wv]=sm; ssd[wv]=sd; }
  __syncthreads();
  if (tid == 0) {
    float M = smx[0], S = ssm[0], D = ssd[0];
    for (int w2=1;w2<4;w2++) {
      float nm = fmaxf(M, smx[w2]);
      S = S*__expf(M-nm) + ssm[w2]*__expf(smx[w2]-nm);
      M = nm; D += ssd[w2];
    }
    rowmax[m] = M; rowsum[m] = S;
    sgate[m] = 1.f/(1.f + __expf(-(D + swb[0])));
  }
}

// ---------------- finalize: log(softmax*s + 1e-6) over V, pointer softmax z over NE ----------------
__global__ __launch_bounds__(256) void fin_k(float* __restrict__ out,
    const float* __restrict__ dec, const float* __restrict__ ents, const int* __restrict__ entlens,
    const float* __restrict__ rowmax, const float* __restrict__ rowsum, const float* __restrict__ sgate)
{
  int m = blockIdx.x, tid = threadIdx.x;
  int b = m >> 8;
  __shared__ float dl[512];
  for (int i = tid; i < 512; i += 256) dl[i] = dec[((long)m<<9) + i];
  __syncthreads();
  float s = sgate[m];
  if (tid < 64) {
    int n = tid;
    const float* ep = ents + (((long)((b<<6)+n)) << 9);
    float uq = 0.f;
    for (int k=0;k<512;k+=4)
      uq += dl[k]*ep[k] + dl[k+1]*ep[k+1] + dl[k+2]*ep[k+2] + dl[k+3]*ep[k+3];
    if (n > entlens[b]) uq = -1e30f;
    float mx = uq;
    #pragma unroll
    for (int off=32; off>0; off>>=1) mx = fmaxf(mx, __shfl_xor(mx, off));
    float e = __expf(uq - mx);
    float sum = e;
    #pragma unroll
    for (int off=32; off>0; off>>=1) sum += __shfl_xor(sum, off);
    float z = (e/sum) * (1.f - s);
    out[(long)m*RS + VOCAB + n] = __logf(z + 1e-6f);
    out[(long)MROWS*RS + ((long)m<<6) + n] = z;     // output 1
  }
  float mx = rowmax[m], inv = 1.f/rowsum[m];
  for (int c = tid; c < VOCAB; c += 256) {
    long idx = (long)m*RS + c;
    float x = out[idx];
    out[idx] = __logf(__expf(x - mx)*inv*s + 1e-6f);
  }
}

// ---------------- launch ----------------
extern "C" void kernel_launch(void* const* d_in, const int* in_sizes, int n_in,
                              void* d_out, int out_size, void* d_ws, size_t ws_size,
                              hipStream_t stream)
{
  const int*   outp    = (const int*)d_in[0];
  const float* ents    = (const float*)d_in[1];
  const int*   entlens = (const int*)d_in[2];
  const float* emb     = (const float*)d_in[3];
  const float* W_ih    = (const float*)d_in[4];
  const float* W_hh    = (const float*)d_in[5];
  const float* b_ih    = (const float*)d_in[6];
  const float* b_hh    = (const float*)d_in[7];
  const float* Wq      = (const float*)d_in[8];
  const float* Wk      = (const float*)d_in[9];
  const float* Wv      = (const float*)d_in[10];
  const float* out_W   = (const float*)d_in[11];
  const float* out_b   = (const float*)d_in[12];
  const float* sw_W    = (const float*)d_in[13];
  const float* sw_b    = (const float*)d_in[14];
  const float* mattn_W = (const float*)d_in[15];
  const float* mattn_b = (const float*)d_in[16];
  float* out = (float*)d_out;
  (void)in_sizes; (void)n_in; (void)out_size; (void)ws_size;

  char* w = (char*)d_ws;
  size_t off = 0;
  auto alloc = [&](size_t bytes) -> char* {
    char* p = w + off; off += bytes; off = (off + 255) & ~(size_t)255; return p;
  };
  _Float16* outW_h = (_Float16*)alloc((size_t)VOCAB*1024*2);   // 65.5 MB
  _Float16* l_h    = (_Float16*)alloc((size_t)MROWS*1024*2);
  _Float16* l_lo   = (_Float16*)alloc((size_t)MROWS*1024*2);
  float*    gpre   = (float*)alloc((size_t)MROWS*2048*4);      // 16 MB (aliased by Af post-rnn)
  _Float16* Wihk_h = (_Float16*)alloc((size_t)2048*512*2);
  _Float16* Wiha16 = (_Float16*)alloc((size_t)2048*512*2);
  _Float16* Whh16  = (_Float16*)alloc((size_t)2048*512*2);
  _Float16* emb_h  = (_Float16*)alloc((size_t)2048*512*2);
  _Float16* ents_h = (_Float16*)alloc((size_t)512*512*2);
  _Float16* Wk_h   = (_Float16*)alloc((size_t)512*512*2);
  _Float16* Wv_h   = (_Float16*)alloc((size_t)512*512*2);
  _Float16* WqT16  = (_Float16*)alloc((size_t)512*512*2);
  _Float16* mat_h  = (_Float16*)alloc((size_t)512*1024*2);
  _Float16* mat_lo = (_Float16*)alloc((size_t)512*1024*2);
  float*    Kb     = (float*)alloc((size_t)512*512*4);
  float*    Vb     = (float*)alloc((size_t)512*512*4);
  _Float16* Kb16   = (_Float16*)alloc((size_t)512*512*2);
  float*    Mh     = (float*)alloc((size_t)4*512*512*4);       // 4 MB
  _Float16* VblkS  = (_Float16*)alloc((size_t)2048*512*2);     // 2 MB
  _Float16* VblkT  = (_Float16*)alloc((size_t)8*512*256*2);    // 2 MB
  float*    WVall  = (float*)alloc((size_t)2048*2048*4);       // 16 MB
  _Float16* Pg     = (_Float16*)alloc((size_t)8*256*256*2);    // 1 MB
  float*    dec    = (float*)alloc((size_t)MROWS*512*4);
  float*    bsum   = (float*)alloc(2048*4);
  u64*      hxe    = (u64*)alloc((size_t)4096*8);
  u64*      Se     = (u64*)alloc((size_t)2048*8);
  float*    rmax   = (float*)alloc(2048*4);
  float*    rsum   = (float*)alloc(2048*4);
  float*    sg     = (float*)alloc(2048*4);
  float*    Af     = gpre;   // alias: gpre dead after rnn_k; Af written by avP after

  auto cast = [&](const float* s, _Float16* d, int total, int sld, int soff, int dld, int doff,
                  int cs, int lo, float mul, int tr) {
    cast_k<<<(total+255)/256, 256, 0, stream>>>(s, d, total, sld, soff, dld, doff, cs, lo, mul, tr);
  };
  auto gemm = [&](const _Float16* A, const _Float16* B, float* C, const float* bias,
                  int M, int N, int K, int lda, int ldb, int ldc, int accum,
                  int gx, int gy, int gz, long sA, long sB, long sC) {
    gemm_k<<<dim3(gx,gy,gz), 256, 0, stream>>>(A, B, C, bias, M, N, K, lda, ldb, ldc, accum, sA, sB, sC);
  };

  cast(out_W,   outW_h, VOCAB*1024, 1024, 0,   1024, 0,   10, 0, 1.f, 0);
  cast(W_ih,    Wihk_h, 2048*512,   1024, 512, 512,  0,   9,  0, 1.f, 0);
  cast(W_ih,    Wiha16, 2048*512,   1024, 0,   512,  0,   9,  0, 1.f, 0);
  cast(W_hh,    Whh16,  2048*512,   512,  0,   512,  0,   9,  0, 1.f, 0);
  cast(Wq,      WqT16,  512*512,    512,  0,   512,  0,   9,  0, 1.f, 1);  // transposed
  cast(Wk,      Wk_h,   512*512,    512,  0,   512,  0,   9,  0, 1.f, 0);
  cast(Wv,      Wv_h,   512*512,    512,  0,   512,  0,   9,  0, 1.f, 0);
  cast(mattn_W, mat_h,  512*1024,   1024, 0,   1024, 0,   10, 0, 1.f, 0);
  cast(mattn_W, mat_lo, 512*1024,   1024, 0,   1024, 0,   10, 1, 1.f, 0);
  cast(ents,    ents_h, 512*512,    512,  0,   512,  0,   9,  0, 1.f, 0);

  embgather_k<<<4096, 256, 0, stream>>>(emb, outp, emb_h);
  prep_k<<<16, 256, 0, stream>>>(b_ih, b_hh, ents, bsum, hxe, Se);

  gemm(ents_h, Wk_h,   Kb,   nullptr, 512,  512,  512, 512, 512, 512,  0,  4,  4, 1, 0,0,0);
  gemm(ents_h, Wv_h,   Vb,   nullptr, 512,  512,  512, 512, 512, 512,  0,  4,  4, 1, 0,0,0);
  gemm(emb_h,  Wihk_h, gpre, bsum,    2048, 2048, 512, 512, 512, 2048, 0, 16, 16, 1, 0,0,0);

  cast(Kb, Kb16, 512*512, 512, 0, 512, 0, 9, 0, SCALE, 0);    // fold 1/sqrt(512) into K
  vblk_k<<<4096, 256, 0, stream>>>(Vb, VblkS, VblkT);

  for (int h = 0; h < 4; h++)                                  // M_h = (K_h*s) @ Wq_h^T
    gemm(Kb16 + h*128, WqT16 + h*128, Mh + (long)h*512*512, nullptr,
         512, 512, 128, 512, 512, 512, 0, 4, 4, 1, 0,0,0);
  gemm(Wiha16, VblkS, WVall, nullptr,                          // WV = W_ih_a @ Vblk^T
       2048, 2048, 512, 512, 512, 2048, 0, 16, 16, 1, 0,0,0);

  rnn_k<<<256, 512, 0, stream>>>(gpre, Whh16, Mh, WVall, entlens, hxe, Se, Pg, l_h, l_lo);

  // postpass: A[b] = P[b] @ Vblk[b]^T  (batched), then cast into l_h/l_lo a-part
  gemm(Pg, VblkT, Af, nullptr, 256, 512, 256, 256, 256, 512, 0,
       4, 2, 8, (long)256*256, (long)512*256, (long)256*512);
  cast(Af, l_h,  MROWS*512, 512, 0, 1024, 512, 9, 0, 1.f, 0);
  cast(Af, l_lo, MROWS*512, 512, 0, 1024, 512, 9, 1, 1.f, 0);

  gemm(l_h,  mat_h,  dec, mattn_b, 2048, 512,   1024, 1024, 1024, 512, 0, 4,  16, 1, 0,0,0);
  gemm(l_lo, mat_h,  dec, nullptr, 2048, 512,   1024, 1024, 1024, 512, 1, 4,  16, 1, 0,0,0);
  gemm(l_h,  mat_lo, dec, nullptr, 2048, 512,   1024, 1024, 1024, 512, 1, 4,  16, 1, 0,0,0);
  gemm(l_h,  outW_h, out, out_b,   2048, 32000, 1024, 1024, 1024, RS,  0, 250, 16, 1, 0,0,0);

  stats_k<<<2048, 256, 0, stream>>>(out, l_h, sw_W, sw_b, rmax, rsum, sg);
  fin_k<<<2048, 256, 0, stream>>>(out, dec, ents, entlens, rmax, rsum, sg);
}

// Round 7
// 2031.869 us; speedup vs baseline: 3.3654x; 1.0887x over previous
//
#include <hip/hip_runtime.h>
#include <cstdint>

#define TT 256
#define BB 8
#define NE 64
#define HH 512
#define VOCAB 32000
#define G4 2048
#define RS 32064          // out0 row stride (V + NE)
#define MROWS 2048        // B*T
#define SCALE 0.044194173824159216f  // 1/sqrt(512)

typedef _Float16 h2 __attribute__((ext_vector_type(2)));
typedef _Float16 h8 __attribute__((ext_vector_type(8)));
typedef float f4 __attribute__((ext_vector_type(4)));
typedef unsigned long long u64;

__device__ inline float sigf(float x){ return 1.f/(1.f+__expf(-x)); }

// agent-scope 64-bit payload words: hi32 = epoch, lo32 = f32 bits (single-copy atomic)
__device__ inline u64 g64load(const u64* p){
  return __hip_atomic_load((u64*)p, __ATOMIC_RELAXED, __HIP_MEMORY_SCOPE_AGENT);
}
__device__ inline void g64store(u64* p, u64 v){
  __hip_atomic_store(p, v, __ATOMIC_RELAXED, __HIP_MEMORY_SCOPE_AGENT);
}

// ---------------- casts (f32 -> f16, hi or lo residual, optional scale/transpose) ----------------
__global__ __launch_bounds__(256) void cast_k(const float* __restrict__ src, _Float16* __restrict__ dst,
    int total, int src_ld, int src_off, int dst_ld, int dst_off, int cshift, int lo, float mul, int tr)
{
  int i = blockIdx.x*256 + threadIdx.x;
  if (i >= total) return;
  int c = i & ((1<<cshift)-1);
  int r = i >> cshift;
  float x = src[(long)r*src_ld + src_off + c] * mul;
  _Float16 h = (_Float16)x;
  if (lo) h = (_Float16)(x - (float)h);
  if (tr) dst[(long)c*dst_ld + dst_off + r] = h;
  else    dst[(long)r*dst_ld + dst_off + c] = h;
}

__global__ __launch_bounds__(256) void embgather_k(const float* __restrict__ emb,
    const int* __restrict__ outp, _Float16* __restrict__ dst)
{
  int i = blockIdx.x*256 + threadIdx.x;   // < 2048*512, rows m = t*8+b
  int k = i & 511; int m = i >> 9;
  int t = m >> 3, b = m & 7;
  int tok = outp[b*TT + t];
  dst[i] = (_Float16)emb[(long)tok*HH + k];
}

// prep: bias sum; hx(-1) = mean(ents) epoch-0 payload words; S buffer zero
__global__ __launch_bounds__(256) void prep_k(const float* __restrict__ b_ih, const float* __restrict__ b_hh,
    const float* __restrict__ ents, float* bsum, u64* hxe, u64* Se)
{
  int i = blockIdx.x*256 + threadIdx.x;   // grid 16 -> 4096 threads
  if (i < G4) bsum[i] = b_ih[i] + b_hh[i];
  if (i < BB*HH) {
    int b = i >> 9, j = i & 511;
    float s = 0.f;
    for (int n = 0; n < NE; n++) s += ents[(size_t)((b<<6)+n)*HH + j];
    s *= (1.0f/NE);
    hxe[i] = (u64)__float_as_uint(s);     // epoch 0
  }
  if (i < BB*256) Se[i] = 0ull;
}

// build block-diagonal-expanded V (f16), both row layouts:
// VblkS[(b*256+he)][d] and VblkT[b][d][he], val = (he head == d head) ? V[b][e][d] : 0
__global__ __launch_bounds__(256) void vblk_k(const float* __restrict__ Vb,
    _Float16* __restrict__ VblkS, _Float16* __restrict__ VblkT)
{
  int i = blockIdx.x*256 + threadIdx.x;   // < 8*512*256 = 1,048,576
  int he = i & 255, d = (i >> 8) & 511, b = i >> 17;
  _Float16 v = (_Float16)0.f;
  if ((he >> 6) == (d >> 7)) v = (_Float16)Vb[(((long)((b<<6)|(he&63)))<<9) + d];
  VblkT[(((long)((b<<9)|d))<<8) + he] = v;
  VblkS[(((long)((b<<8)|he))<<9) + d] = v;
}

// ---------------- f16 MFMA GEMM: C[M,N](f32) = A[M,K] * B[N,K]^T (+bias) ----------------
// lda/ldb/ldc explicit; optional batch via blockIdx.z with element strides sA/sB/sC.
__global__ __launch_bounds__(256) void gemm_k(const _Float16* __restrict__ A, const _Float16* __restrict__ Bm,
    float* __restrict__ C, const float* __restrict__ bias,
    int M, int N, int K, int lda, int ldb, int ldc, int accum, long sA, long sB, long sC)
{
  __shared__ __align__(16) _Float16 At[128][40];
  __shared__ __align__(16) _Float16 Bt[128][40];
  int z = blockIdx.z;
  A  += (long)z * sA;  Bm += (long)z * sB;  C += (long)z * sC;
  int tid = threadIdx.x;
  int n0 = blockIdx.x * 128, m0 = blockIdx.y * 128;
  int wave = tid >> 6, lane = tid & 63;
  int mw = (wave & 1) << 6, nw = (wave >> 1) << 6;
  int lr = tid >> 2, lc = (tid & 3) << 3;
  const _Float16* Ap0 = A + (long)(m0 + lr)*lda + lc;
  const _Float16* Ap1 = Ap0 + (long)64*lda;
  const _Float16* Bp0 = Bm + (long)(n0 + lr)*ldb + lc;
  const _Float16* Bp1 = Bp0 + (long)64*ldb;
  f4 acc[4][4] = {};
  int rr = lane & 15, kq = (lane >> 4) << 3;
  for (int kt = 0; kt < K; kt += 32) {
    h8 av0 = *(const h8*)(Ap0 + kt);
    h8 av1 = *(const h8*)(Ap1 + kt);
    h8 bv0 = *(const h8*)(Bp0 + kt);
    h8 bv1 = *(const h8*)(Bp1 + kt);
    __syncthreads();
    *(h8*)&At[lr][lc]    = av0;
    *(h8*)&At[64+lr][lc] = av1;
    *(h8*)&Bt[lr][lc]    = bv0;
    *(h8*)&Bt[64+lr][lc] = bv1;
    __syncthreads();
    h8 af[4], bf[4];
    #pragma unroll
    for (int mt=0;mt<4;mt++) af[mt] = *(const h8*)&At[mw + mt*16 + rr][kq];
    #pragma unroll
    for (int nt=0;nt<4;nt++) bf[nt] = *(const h8*)&Bt[nw + nt*16 + rr][kq];
    #pragma unroll
    for (int mt=0;mt<4;mt++)
      #pragma unroll
      for (int nt=0;nt<4;nt++)
        acc[mt][nt] = __builtin_amdgcn_mfma_f32_16x16x32_f16(af[mt], bf[nt], acc[mt][nt], 0, 0, 0);
  }
  int cc = lane & 15, rq = (lane >> 4) << 2;
  #pragma unroll
  for (int nt=0;nt<4;nt++) {
    int col = n0 + nw + nt*16 + cc;
    float bv = bias ? bias[col] : 0.f;
    #pragma unroll
    for (int mt=0;mt<4;mt++) {
      int row0 = m0 + mw + mt*16 + rq;
      #pragma unroll
      for (int r=0;r<4;r++) {
        long idx = (long)(row0 + r)*ldc + col;
        float v = acc[mt][nt][r] + bv;
        if (accum) C[idx] += v; else C[idx] = v;
      }
    }
  }
}

// ---------------- batch-local persistent RNN: 8 groups x 32 WGs (1 WG/CU) ----------------
// Same exchange algebra as r5 (S = hx@M split across WGs; gates_a = WV@p; A = P@V
// postpass). Conflict-free LDS tilings (Wl2/WVl2 [c][row][slice]: a wave reads 64
// consecutive 16B chunks; hxh reads span one contiguous 128B run per c-iter; A-stage
// stride-64 interleave) and softmax/WVp split across waves 0-3 (one head each,
// quarter-range WVp partials); wave0 sums partials + cell. 2 barriers/step.
// Interlock: hx overwrite(it+2) <- D1 S-poll(it+1) <- all A(it+1) <- their F(it)
// hx-poll complete; Se overwrite(it+1) <- A <- G <- F(it) <- D2(it) <- C2 <- D1 reads.
__global__ __launch_bounds__(512, 1) void rnn_k(
    const float* __restrict__ gates_pre, const _Float16* __restrict__ Whh16,
    const float* __restrict__ Mh, const float* __restrict__ WVall,
    const int* __restrict__ entlens,
    u64* hxe, u64* Se, _Float16* Pg, _Float16* l_h, _Float16* l_lo)
{
  __shared__ __align__(16) _Float16 Wl2[32768];   // 64KB  [8c][64r][8sl][8] Whh tiles
  __shared__ __align__(16) _Float16 WVl2[16384];  // 32KB  [32c][64r][8] WV tiles
  __shared__ __align__(16) float    Ml2[8][512];  // 16KB  score rows (linear)
  __shared__ __align__(16) float    hxs[512];     // staged hx f32
  __shared__ __align__(16) _Float16 hxh[512];     // staged hx f16
  __shared__ __align__(16) _Float16 ph[256];      // p f16 (per-head segments)
  __shared__ float part[4][64];                   // WVp quarter partials
  __shared__ float gsum[64];                      // hh-matvec row sums
  __shared__ float gpl[64];                       // gpre prefetch

  const int tid = threadIdx.x, wg = blockIdx.x;
  const int b = wg >> 5, wgl = wg & 31, u_off = wgl << 4;
  const int lane = tid & 63, wv = tid >> 6;
  const int el = entlens[b];
  const int h_own = wgl >> 3, e_base = (wgl & 7) << 3;  // score rows [8wgl,8wgl+8)
  u64* hxb = hxe + ((long)b << 9);
  u64* Sb  = Se  + ((long)b << 8);

  // ---- one-time: weights -> LDS (tiled) ----
  for (int i = tid; i < 4096; i += 512) {          // Whh h8 chunks -> [c][r][sl], k8c = c*8+sl
    int r = i >> 6, k8c = i & 63;
    int c = k8c >> 3, sl = k8c & 7;
    int grow = ((r >> 4) << 9) + u_off + (r & 15); // gate*512 + 16wgl + u
    *(h8*)&Wl2[((((c << 6) + r) << 3) + sl) << 3] =
        *(const h8*)(Whh16 + ((long)grow << 9) + (k8c << 3));
  }
  for (int i = tid; i < 4096; i += 512) {          // M rows linear f32
    int r = i >> 9, e = i & 511;
    Ml2[r][e] = Mh[((long)h_own << 18) + (((long)((b << 6) + e_base + r)) << 9) + e];
  }
  for (int i = tid; i < 16384; i += 512) {         // WV f32 -> f16 tiled [c][r][8]
    int r = i >> 8, cj = i & 255, c = cj >> 3, j = cj & 7;
    int grow = ((r >> 4) << 9) + u_off + (r & 15);
    WVl2[((((c << 6) + r) << 3) + j)] = (_Float16)WVall[((long)grow << 11) + (b << 8) + cj];
  }
  // ---- stage hx(-1) (epoch 0 from prep, same stream: plain load) ----
  if (tid < 256) {
    u64 w0 = g64load(hxb + 2*tid), w1 = g64load(hxb + 2*tid + 1);
    float f0 = __uint_as_float((unsigned)w0), f1 = __uint_as_float((unsigned)w1);
    hxs[2*tid] = f0; hxs[2*tid+1] = f1;
    hxh[2*tid] = (_Float16)f0; hxh[2*tid+1] = (_Float16)f1;
  }
  __syncthreads();
  float cx = 0.f;
  if (wv == 0 && lane < 16) cx = hxs[u_off + lane];   // cx0 = hx0

  for (int it = 0; it < TT; it++) {
    const unsigned set = (unsigned)(it + 1);
    // ---- A: own S row = hxs . Ml2[wv], stride-64 interleave (bank-free), post tag ----
    {
      float sp = 0.f;
      #pragma unroll
      for (int j = 0; j < 8; j++) sp += hxs[(j << 6) + lane] * Ml2[wv][(j << 6) + lane];
      #pragma unroll
      for (int off = 32; off; off >>= 1) sp += __shfl_xor(sp, off);
      if (lane == 0)
        g64store(Sb + (h_own << 6) + e_base + wv, ((u64)set << 32) | (u64)__float_as_uint(sp));
    }
    if (tid < 64) {   // gpre prefetch
      int col = ((tid >> 4) << 9) + u_off + (tid & 15);
      gpl[tid] = gates_pre[((long)((it << 3) + b) << 11) + col];
    }
    // ---- B: hh matvec; thread (r,sl) handles k-chunks c*8+sl; both reads bank-free ----
    {
      int sl = tid & 7;
      float s = 0.f;
      #pragma unroll
      for (int c = 0; c < 8; c++) {
        union { h8 v; h2 p[4]; } a_, w_;
        a_.v = *(const h8*)&hxh[(c << 6) + (sl << 3)];
        w_.v = *(const h8*)&Wl2[((c << 9) + tid) << 3];
        #pragma unroll
        for (int p = 0; p < 4; p++) s = __builtin_amdgcn_fdot2(a_.p[p], w_.p[p], s, false);
      }
      s += __shfl_xor(s, 1); s += __shfl_xor(s, 2); s += __shfl_xor(s, 4);
      if (sl == 0) gsum[tid >> 3] = s;
    }
    // ---- D1 (waves 0-3): poll S head wv (1 word/lane), softmax, quarter WVp ----
    if (wv < 4) {
      u64 sv = g64load(Sb + (wv << 6) + lane);
      while ((unsigned)(sv >> 32) < set) { __builtin_amdgcn_s_sleep(1); sv = g64load(Sb + (wv << 6) + lane); }
      if (it > 0) {
        float x = __uint_as_float((unsigned)sv);
        if (lane > el) x = -1e30f;
        float mx = x;
        #pragma unroll
        for (int off = 32; off; off >>= 1) mx = fmaxf(mx, __shfl_xor(mx, off));
        float e = __expf(x - mx), sm = e;
        #pragma unroll
        for (int off = 32; off; off >>= 1) sm += __shfl_xor(sm, off);
        float p = e / sm;
        _Float16 p16 = (_Float16)p;
        ph[(wv << 6) + lane] = p16;
        float s = 0.f;           // partial WVp over entities [64wv,64wv+64), row = lane
        #pragma unroll
        for (int cc = 0; cc < 8; cc++) {
          int c = (wv << 3) + cc;
          union { h8 v; h2 p[4]; } pv, wv_;
          pv.v  = *(const h8*)&ph[(wv << 6) + (cc << 3)];
          wv_.v = *(const h8*)&WVl2[(((c << 6) + lane) << 3)];
          #pragma unroll
          for (int p2 = 0; p2 < 4; p2++) s = __builtin_amdgcn_fdot2(pv.p[p2], wv_.p[p2], s, false);
        }
        part[wv][lane] = s;
        Pg[((long)((b << 8) + (it - 1)) << 8) + (wv << 6) + lane] = p16;
      }
    }
    __syncthreads();   // C2: gsum + part visible; hxs/hxh free after this
    // ---- D2 (wave0): sum partials + cell + hx post ----
    if (wv == 0) {
      float wvp = (it > 0) ? (part[0][lane] + part[1][lane] + part[2][lane] + part[3][lane]) : 0.f;
      float gv = gpl[lane] + gsum[lane] + wvp;
      float gi = __shfl(gv, lane & 15);
      float gf = __shfl(gv, 16 + (lane & 15));
      float gg = __shfl(gv, 32 + (lane & 15));
      float go = __shfl(gv, 48 + (lane & 15));
      if (lane < 16) {
        float c_ = sigf(gf)*cx + sigf(gi)*tanhf(gg);
        cx = c_;
        float h = sigf(go)*tanhf(c_);
        int j = u_off + lane;
        g64store(hxb + j, ((u64)set << 32) | (u64)__float_as_uint(h));
        _Float16 hh_ = (_Float16)h;
        long li = ((long)((b << 8) + it)) << 10;
        l_h[li + j]  = hh_;
        l_lo[li + j] = (_Float16)(h - (float)hh_);
      }
    }
    // ---- F: poll hx(it) tag it+1, restage ----
    if (tid < 256) {
      u64 w0 = g64load(hxb + 2*tid), w1 = g64load(hxb + 2*tid + 1);
      while ((unsigned)(w0 >> 32) < set) { __builtin_amdgcn_s_sleep(1); w0 = g64load(hxb + 2*tid); }
      while ((unsigned)(w1 >> 32) < set) { __builtin_amdgcn_s_sleep(1); w1 = g64load(hxb + 2*tid + 1); }
      float f0 = __uint_as_float((unsigned)w0), f1 = __uint_as_float((unsigned)w1);
      hxs[2*tid] = f0; hxs[2*tid+1] = f1;
      hxh[2*tid] = (_Float16)f0; hxh[2*tid+1] = (_Float16)f1;
    }
    __syncthreads();   // G
  }
  // ---- epilogue: p(255) from hx(255), tag 257 ----
  {
    float sp = 0.f;
    #pragma unroll
    for (int j = 0; j < 8; j++) sp += hxs[(j << 6) + lane] * Ml2[wv][(j << 6) + lane];
    #pragma unroll
    for (int off = 32; off; off >>= 1) sp += __shfl_xor(sp, off);
    if (lane == 0)
      g64store(Sb + (h_own << 6) + e_base + wv, ((u64)257u << 32) | (u64)__float_as_uint(sp));
    if (wv < 4) {
      u64 sv = g64load(Sb + (wv << 6) + lane);
      while ((unsigned)(sv >> 32) < 257u) { __builtin_amdgcn_s_sleep(1); sv = g64load(Sb + (wv << 6) + lane); }
      float x = __uint_as_float((unsigned)sv);
      if (lane > el) x = -1e30f;
      float mx = x;
      #pragma unroll
      for (int off = 32; off; off >>= 1) mx = fmaxf(mx, __shfl_xor(mx, off));
      float e = __expf(x - mx), sm = e;
      #pragma unroll
      for (int off = 32; off; off >>= 1) sm += __shfl_xor(sm, off);
      Pg[((long)((b << 8) + 255) << 8) + (wv << 6) + lane] = (_Float16)(e / sm);
    }
  }
}

// ---------------- online softmax stats over V + sigmoid switch gate ----------------
__global__ __launch_bounds__(256) void stats_k(const float* __restrict__ out0,
    const _Float16* __restrict__ l_h, const float* __restrict__ swW, const float* __restrict__ swb,
    float* rowmax, float* rowsum, float* sgate)
{
  int m = blockIdx.x, tid = threadIdx.x;
  const float* row = out0 + (long)m*RS;
  float mx = -1e30f, sm = 0.f;
  for (int c = tid; c < VOCAB; c += 256) {
    float x = row[c];
    float nm = fmaxf(mx, x);
    sm = sm*__expf(mx-nm) + __expf(x-nm);
    mx = nm;
  }
  float sd = 0.f;
  const _Float16* lr_ = l_h + ((long)m << 10);
  for (int k = tid; k < 1024; k += 256) sd += (float)lr_[k] * swW[k];
  #pragma unroll
  for (int off=32; off>0; off>>=1) {
    float omx = __shfl_xor(mx, off), osm = __shfl_xor(sm, off);
    float nm = fmaxf(mx, omx);
    sm = sm*__expf(mx-nm) + osm*__expf(omx-nm);
    mx = nm;
    sd += __shfl_xor(sd, off);
  }
  __shared__ float smx[4], ssm[4], ssd[4];
  int wv = tid >> 6;
  if ((tid & 63) == 0) { smx[wv]=mx; ssm[wv]=sm; ssd[wv]=sd; }
  __syncthreads();
  if (tid == 0) {
    float M = smx[0], S = ssm[0], D = ssd[0];
    for (int w2=1;w2<4;w2++) {
      float nm = fmaxf(M, smx[w2]);
      S = S*__expf(M-nm) + ssm[w2]*__expf(smx[w2]-nm);
      M = nm; D += ssd[w2];
    }
    rowmax[m] = M; rowsum[m] = S;
    sgate[m] = 1.f/(1.f + __expf(-(D + swb[0])));
  }
}

// ---------------- finalize: log(softmax*s + 1e-6) over V, pointer softmax z over NE ----------------
__global__ __launch_bounds__(256) void fin_k(float* __restrict__ out,
    const float* __restrict__ dec, const float* __restrict__ ents, const int* __restrict__ entlens,
    const float* __restrict__ rowmax, const float* __restrict__ rowsum, const float* __restrict__ sgate)
{
  int m = blockIdx.x, tid = threadIdx.x;
  int b = m >> 8;
  __shared__ float dl[512];
  for (int i = tid; i < 512; i += 256) dl[i] = dec[((long)m<<9) + i];
  __syncthreads();
  float s = sgate[m];
  if (tid < 64) {
    int n = tid;
    const float* ep = ents + (((long)((b<<6)+n)) << 9);
    float uq = 0.f;
    for (int k=0;k<512;k+=4)
      uq += dl[k]*ep[k] + dl[k+1]*ep[k+1] + dl[k+2]*ep[k+2] + dl[k+3]*ep[k+3];
    if (n > entlens[b]) uq = -1e30f;
    float mx = uq;
    #pragma unroll
    for (int off=32; off>0; off>>=1) mx = fmaxf(mx, __shfl_xor(mx, off));
    float e = __expf(uq - mx);
    float sum = e;
    #pragma unroll
    for (int off=32; off>0; off>>=1) sum += __shfl_xor(sum, off);
    float z = (e/sum) * (1.f - s);
    out[(long)m*RS + VOCAB + n] = __logf(z + 1e-6f);
    out[(long)MROWS*RS + ((long)m<<6) + n] = z;     // output 1
  }
  float mx = rowmax[m], inv = 1.f/rowsum[m];
  for (int c = tid; c < VOCAB; c += 256) {
    long idx = (long)m*RS + c;
    float x = out[idx];
    out[idx] = __logf(__expf(x - mx)*inv*s + 1e-6f);
  }
}

// ---------------- launch ----------------
extern "C" void kernel_launch(void* const* d_in, const int* in_sizes, int n_in,
                              void* d_out, int out_size, void* d_ws, size_t ws_size,
                              hipStream_t stream)
{
  const int*   outp    = (const int*)d_in[0];
  const float* ents    = (const float*)d_in[1];
  const int*   entlens = (const int*)d_in[2];
  const float* emb     = (const float*)d_in[3];
  const float* W_ih    = (const float*)d_in[4];
  const float* W_hh    = (const float*)d_in[5];
  const float* b_ih    = (const float*)d_in[6];
  const float* b_hh    = (const float*)d_in[7];
  const float* Wq      = (const float*)d_in[8];
  const float* Wk      = (const float*)d_in[9];
  const float* Wv      = (const float*)d_in[10];
  const float* out_W   = (const float*)d_in[11];
  const float* out_b   = (const float*)d_in[12];
  const float* sw_W    = (const float*)d_in[13];
  const float* sw_b    = (const float*)d_in[14];
  const float* mattn_W = (const float*)d_in[15];
  const float* mattn_b = (const float*)d_in[16];
  float* out = (float*)d_out;
  (void)in_sizes; (void)n_in; (void)out_size; (void)ws_size;

  char* w = (char*)d_ws;
  size_t off = 0;
  auto alloc = [&](size_t bytes) -> char* {
    char* p = w + off; off += bytes; off = (off + 255) & ~(size_t)255; return p;
  };
  _Float16* outW_h = (_Float16*)alloc((size_t)VOCAB*1024*2);   // 65.5 MB
  _Float16* l_h    = (_Float16*)alloc((size_t)MROWS*1024*2);
  _Float16* l_lo   = (_Float16*)alloc((size_t)MROWS*1024*2);
  float*    gpre   = (float*)alloc((size_t)MROWS*2048*4);      // 16 MB (aliased by Af post-rnn)
  _Float16* Wihk_h = (_Float16*)alloc((size_t)2048*512*2);
  _Float16* Wiha16 = (_Float16*)alloc((size_t)2048*512*2);
  _Float16* Whh16  = (_Float16*)alloc((size_t)2048*512*2);
  _Float16* emb_h  = (_Float16*)alloc((size_t)2048*512*2);
  _Float16* ents_h = (_Float16*)alloc((size_t)512*512*2);
  _Float16* Wk_h   = (_Float16*)alloc((size_t)512*512*2);
  _Float16* Wv_h   = (_Float16*)alloc((size_t)512*512*2);
  _Float16* WqT16  = (_Float16*)alloc((size_t)512*512*2);
  _Float16* mat_h  = (_Float16*)alloc((size_t)512*1024*2);
  _Float16* mat_lo = (_Float16*)alloc((size_t)512*1024*2);
  float*    Kb     = (float*)alloc((size_t)512*512*4);
  float*    Vb     = (float*)alloc((size_t)512*512*4);
  _Float16* Kb16   = (_Float16*)alloc((size_t)512*512*2);
  float*    Mh     = (float*)alloc((size_t)4*512*512*4);       // 4 MB
  _Float16* VblkS  = (_Float16*)alloc((size_t)2048*512*2);     // 2 MB
  _Float16* VblkT  = (_Float16*)alloc((size_t)8*512*256*2);    // 2 MB
  float*    WVall  = (float*)alloc((size_t)2048*2048*4);       // 16 MB
  _Float16* Pg     = (_Float16*)alloc((size_t)8*256*256*2);    // 1 MB
  float*    dec    = (float*)alloc((size_t)MROWS*512*4);
  float*    bsum   = (float*)alloc(2048*4);
  u64*      hxe    = (u64*)alloc((size_t)4096*8);
  u64*      Se     = (u64*)alloc((size_t)2048*8);
  float*    rmax   = (float*)alloc(2048*4);
  float*    rsum   = (float*)alloc(2048*4);
  float*    sg     = (float*)alloc(2048*4);
  float*    Af     = gpre;   // alias: gpre dead after rnn_k; Af written by avP after

  auto cast = [&](const float* s, _Float16* d, int total, int sld, int soff, int dld, int doff,
                  int cs, int lo, float mul, int tr) {
    cast_k<<<(total+255)/256, 256, 0, stream>>>(s, d, total, sld, soff, dld, doff, cs, lo, mul, tr);
  };
  auto gemm = [&](const _Float16* A, const _Float16* B, float* C, const float* bias,
                  int M, int N, int K, int lda, int ldb, int ldc, int accum,
                  int gx, int gy, int gz, long sA, long sB, long sC) {
    gemm_k<<<dim3(gx,gy,gz), 256, 0, stream>>>(A, B, C, bias, M, N, K, lda, ldb, ldc, accum, sA, sB, sC);
  };

  cast(out_W,   outW_h, VOCAB*1024, 1024, 0,   1024, 0,   10, 0, 1.f, 0);
  cast(W_ih,    Wihk_h, 2048*512,   1024, 512, 512,  0,   9,  0, 1.f, 0);
  cast(W_ih,    Wiha16, 2048*512,   1024, 0,   512,  0,   9,  0, 1.f, 0);
  cast(W_hh,    Whh16,  2048*512,   512,  0,   512,  0,   9,  0, 1.f, 0);
  cast(Wq,      WqT16,  512*512,    512,  0,   512,  0,   9,  0, 1.f, 1);  // transposed
  cast(Wk,      Wk_h,   512*512,    512,  0,   512,  0,   9,  0, 1.f, 0);
  cast(Wv,      Wv_h,   512*512,    512,  0,   512,  0,   9,  0, 1.f, 0);
  cast(mattn_W, mat_h,  512*1024,   1024, 0,   1024, 0,   10, 0, 1.f, 0);
  cast(mattn_W, mat_lo, 512*1024,   1024, 0,   1024, 0,   10, 1, 1.f, 0);
  cast(ents,    ents_h, 512*512,    512,  0,   512,  0,   9,  0, 1.f, 0);

  embgather_k<<<4096, 256, 0, stream>>>(emb, outp, emb_h);
  prep_k<<<16, 256, 0, stream>>>(b_ih, b_hh, ents, bsum, hxe, Se);

  gemm(ents_h, Wk_h,   Kb,   nullptr, 512,  512,  512, 512, 512, 512,  0,  4,  4, 1, 0,0,0);
  gemm(ents_h, Wv_h,   Vb,   nullptr, 512,  512,  512, 512, 512, 512,  0,  4,  4, 1, 0,0,0);
  gemm(emb_h,  Wihk_h, gpre, bsum,    2048, 2048, 512, 512, 512, 2048, 0, 16, 16, 1, 0,0,0);

  cast(Kb, Kb16, 512*512, 512, 0, 512, 0, 9, 0, SCALE, 0);    // fold 1/sqrt(512) into K
  vblk_k<<<4096, 256, 0, stream>>>(Vb, VblkS, VblkT);

  for (int h = 0; h < 4; h++)                                  // M_h = (K_h*s) @ Wq_h^T
    gemm(Kb16 + h*128, WqT16 + h*128, Mh + (long)h*512*512, nullptr,
         512, 512, 128, 512, 512, 512, 0, 4, 4, 1, 0,0,0);
  gemm(Wiha16, VblkS, WVall, nullptr,                          // WV = W_ih_a @ Vblk^T
       2048, 2048, 512, 512, 512, 2048, 0, 16, 16, 1, 0,0,0);

  rnn_k<<<256, 512, 0, stream>>>(gpre, Whh16, Mh, WVall, entlens, hxe, Se, Pg, l_h, l_lo);

  // postpass: A[b] = P[b] @ Vblk[b]^T  (batched), then cast into l_h/l_lo a-part
  gemm(Pg, VblkT, Af, nullptr, 256, 512, 256, 256, 256, 512, 0,
       4, 2, 8, (long)256*256, (long)512*256, (long)256*512);
  cast(Af, l_h,  MROWS*512, 512, 0, 1024, 512, 9, 0, 1.f, 0);
  cast(Af, l_lo, MROWS*512, 512, 0, 1024, 512, 9, 1, 1.f, 0);

  gemm(l_h,  mat_h,  dec, mattn_b, 2048, 512,   1024, 1024, 1024, 512, 0, 4,  16, 1, 0,0,0);
  gemm(l_lo, mat_h,  dec, nullptr, 2048, 512,   1024, 1024, 1024, 512, 1, 4,  16, 1, 0,0,0);
  gemm(l_h,  mat_lo, dec, nullptr, 2048, 512,   1024, 1024, 1024, 512, 1, 4,  16, 1, 0,0,0);
  gemm(l_h,  outW_h, out, out_b,   2048, 32000, 1024, 1024, 1024, RS,  0, 250, 16, 1, 0,0,0);

  stats_k<<<2048, 256, 0, stream>>>(out, l_h, sw_W, sw_b, rmax, rsum, sg);
  fin_k<<<2048, 256, 0, stream>>>(out, dec, ents, entlens, rmax, rsum, sg);
}